// Round 3
// baseline (319.053 us; speedup 1.0000x reference)
//
#include <hip/hip_runtime.h>

// Problem constants (from reference)
#define BATCH 16384
#define CNUM  8
#define DIN   256
#define NH0   512
#define NH1   256

#define BT       64            // batch rows per block (fallback kernel)
#define BTM      32            // batch rows per block (main kernel)
#define NTHREADS 512           // 8 waves

#define X_ELEMS  (BATCH * DIN)        // 4194304
#define W0_ELEMS (CNUM * NH0 * DIN)   // 1048576
#define W1_ELEMS (CNUM * NH1 * NH0)   // 1048576
#define WS_NEED  ((size_t)(X_ELEMS + W0_ELEMS + W1_ELEMS) * 2)  // 12.6 MB bf16

typedef __bf16 bf16x8 __attribute__((ext_vector_type(8)));
typedef __bf16 bf16x4 __attribute__((ext_vector_type(4)));
typedef float  f32x4  __attribute__((ext_vector_type(4)));
typedef float  f32x8  __attribute__((ext_vector_type(8)));

// ---------------------------------------------------------------------------
// Prep: fp32 -> bf16 for x, W0, W1 into ws.  786432 chunks x 8 elems.
// ---------------------------------------------------------------------------
__global__ __launch_bounds__(256)
void cvt_bf16(const float* __restrict__ x, const float* __restrict__ W0,
              const float* __restrict__ W1, __bf16* __restrict__ ws) {
    const int i = blockIdx.x * 256 + threadIdx.x;   // chunk of 8 elems
    const float* src;
    __bf16* dst;
    int off;
    if (i < X_ELEMS / 8)                 { src = x;  dst = ws;                        off = i * 8; }
    else if (i < (X_ELEMS + W0_ELEMS)/8) { src = W0; dst = ws + X_ELEMS;             off = (i - X_ELEMS/8) * 8; }
    else                                 { src = W1; dst = ws + X_ELEMS + W0_ELEMS;  off = (i - (X_ELEMS + W0_ELEMS)/8) * 8; }
    f32x8 v = *(const f32x8*)(src + off);
    bf16x8 r;
    #pragma unroll
    for (int j = 0; j < 8; ++j) r[j] = (__bf16)v[j];
    *(bf16x8*)(dst + off) = r;
}

// ---------------------------------------------------------------------------
// Main fused kernel (bf16 path), BTM = 32 rows/block for 4 blocks/CU.
// grid = (BATCH/BTM)*CNUM; c = blockIdx&7 (XCD round-robin -> W[c] L2-resident).
//
// LDS h0s = 32 granules x 512 elems (1 KB each), granule g = kw*2 + bt where
//   kw = n>>5 (16 k-chunks), bt = m>>4 (2 batch tiles). Frag-major: layer-1
//   ds_read_b128 is lane-contiguous -> conflict-free.
// xs (frag-major x tile, 16 KB) aliases granules 16..31 during layer 0.
// Layer 0 runs in two n-halves: half 0 writes granules 0..15 (disjoint from
// xs, no barrier needed); half 1 writes 16..31 after one barrier.
//
// Per-wave registers: acc 2x2 f32x4 = 16, acc1 2x2 f32x4 = 16 -> fits the
// 64-VGPR budget for 8 waves/SIMD (forced via __launch_bounds__(512,8)).
// ---------------------------------------------------------------------------
__global__ __launch_bounds__(NTHREADS, 8)
void confounder_main(const __bf16* __restrict__ ws,
                     const float* __restrict__ b0,
                     const float* __restrict__ b1,
                     const float* __restrict__ W2,
                     const float* __restrict__ b2,
                     float* __restrict__ out) {
    __shared__ __align__(16) __bf16 h0s[BTM * NH0];  // 32 KB granule-major
    __shared__ float red[8][BTM];                    // 1 KB
    __bf16* xs = h0s + 16 * 512;                     // upper 16 KB alias for x tile

    const __bf16* xbf = ws;
    const __bf16* w0b = ws + X_ELEMS;
    const __bf16* w1b = ws + X_ELEMS + W0_ELEMS;

    const int c    = blockIdx.x & 7;
    const int mb   = blockIdx.x >> 3;
    const int row0 = mb * BTM;

    const int tid  = threadIdx.x;
    const int w    = tid >> 6;    // wave 0..7
    const int lane = tid & 63;
    const int l15  = lane & 15;
    const int l4   = lane >> 4;   // 0..3

    // ---- stage x tile into LDS (granules 16..31), frag-major --------------
    // granule p = mt*8+ks; lane's 8 elems: row mt*16+l15, cols ks*32+8*l4..+7
    #pragma unroll
    for (int q = 0; q < 2; ++q) {
        const int p  = w * 2 + q;             // 0..15
        const int mt = p >> 3, ks = p & 7;
        bf16x8 v = *(const bf16x8*)(xbf + (size_t)(row0 + mt * 16 + l15) * DIN + ks * 32 + 8 * l4);
        *(bf16x8*)(xs + (p * 64 + lane) * 8) = v;
    }

    // W0 rows for half h: n = h*256 + w*32 + at*16 + l15
    const __bf16* w0r = w0b + ((size_t)c * NH0 + w * 32 + l15) * DIN + 8 * l4;

    // cross-barrier prefetch: half-0, ks=0 fragments
    bf16x8 a0 = *(const bf16x8*)(w0r);
    bf16x8 a1 = *(const bf16x8*)(w0r + 16 * DIN);
    __syncthreads();

    f32x4 acc[2][2];   // [at][bt] — 16 regs

    // ================= Layer 0, half h = 0 (n in [0,256)) ==================
    #pragma unroll
    for (int at = 0; at < 2; ++at)
        #pragma unroll
        for (int bt = 0; bt < 2; ++bt)
            acc[at][bt] = (f32x4){0.f, 0.f, 0.f, 0.f};

    #pragma unroll
    for (int ks = 0; ks < 8; ++ks) {
        bf16x8 na0 = a0, na1 = a1;
        if (ks < 7) {
            na0 = *(const bf16x8*)(w0r + (ks + 1) * 32);
            na1 = *(const bf16x8*)(w0r + 16 * DIN + (ks + 1) * 32);
        }
        #pragma unroll
        for (int bt = 0; bt < 2; ++bt) {
            bf16x8 bf = *(const bf16x8*)(xs + ((bt * 8 + ks) * 64 + lane) * 8);
            acc[0][bt] = __builtin_amdgcn_mfma_f32_16x16x32_bf16(a0, bf, acc[0][bt], 0, 0, 0);
            acc[1][bt] = __builtin_amdgcn_mfma_f32_16x16x32_bf16(a1, bf, acc[1][bt], 0, 0, 0);
        }
        a0 = na0; a1 = na1;
    }

    // prefetch half-1 ks=0 while epilogue-0 runs
    const __bf16* w0r1 = w0r + 256 * DIN;
    bf16x8 p0 = *(const bf16x8*)(w0r1);
    bf16x8 p1 = *(const bf16x8*)(w0r1 + 16 * DIN);

    // epilogue half 0 -> granules g = w*2 + bt (0..15); xs untouched
    //   n = w*32 + at*16 + 4*l4 + r, m = bt*16 + l15
    //   sub = (nr>>3)*128 + l15*8 + (nr&7), nr = at*16 + 4*l4 + r
    #pragma unroll
    for (int at = 0; at < 2; ++at) {
        const int nb = w * 32 + at * 16 + 4 * l4;
        const f32x4 b4 = *(const f32x4*)(b0 + c * NH0 + nb);
        const int sub = (at * 2 + (l4 >> 1)) * 128 + l15 * 8 + 4 * (l4 & 1);
        #pragma unroll
        for (int bt = 0; bt < 2; ++bt) {
            const int g = w * 2 + bt;
            bf16x4 pk;
            #pragma unroll
            for (int r = 0; r < 4; ++r) {
                float v = acc[at][bt][r] + b4[r];
                v = v > 0.f ? v : 0.f;
                pk[r] = (__bf16)v;
            }
            *(bf16x4*)(&h0s[g * 512 + sub]) = pk;
        }
    }

    // ================= Layer 0, half h = 1 (n in [256,512)) ================
    a0 = p0; a1 = p1;
    #pragma unroll
    for (int at = 0; at < 2; ++at)
        #pragma unroll
        for (int bt = 0; bt < 2; ++bt)
            acc[at][bt] = (f32x4){0.f, 0.f, 0.f, 0.f};

    #pragma unroll
    for (int ks = 0; ks < 8; ++ks) {
        bf16x8 na0 = a0, na1 = a1;
        if (ks < 7) {
            na0 = *(const bf16x8*)(w0r1 + (ks + 1) * 32);
            na1 = *(const bf16x8*)(w0r1 + 16 * DIN + (ks + 1) * 32);
        }
        #pragma unroll
        for (int bt = 0; bt < 2; ++bt) {
            bf16x8 bf = *(const bf16x8*)(xs + ((bt * 8 + ks) * 64 + lane) * 8);
            acc[0][bt] = __builtin_amdgcn_mfma_f32_16x16x32_bf16(a0, bf, acc[0][bt], 0, 0, 0);
            acc[1][bt] = __builtin_amdgcn_mfma_f32_16x16x32_bf16(a1, bf, acc[1][bt], 0, 0, 0);
        }
        a0 = na0; a1 = na1;
    }

    // prefetch W1 ks=0 (rides through the barriers below)
    const __bf16* w1r = w1b + ((size_t)c * NH1 + w * 32 + l15) * NH0 + 8 * l4;
    bf16x8 q0 = *(const bf16x8*)(w1r);
    bf16x8 q1 = *(const bf16x8*)(w1r + 16 * NH0);

    __syncthreads();   // all waves done reading xs before granules 16..31 write

    // epilogue half 1 -> granules g = 16 + w*2 + bt
    #pragma unroll
    for (int at = 0; at < 2; ++at) {
        const int nb = 256 + w * 32 + at * 16 + 4 * l4;
        const f32x4 b4 = *(const f32x4*)(b0 + c * NH0 + nb);
        const int sub = (at * 2 + (l4 >> 1)) * 128 + l15 * 8 + 4 * (l4 & 1);
        #pragma unroll
        for (int bt = 0; bt < 2; ++bt) {
            const int g = 16 + w * 2 + bt;
            bf16x4 pk;
            #pragma unroll
            for (int r = 0; r < 4; ++r) {
                float v = acc[at][bt][r] + b4[r];
                v = v > 0.f ? v : 0.f;
                pk[r] = (__bf16)v;
            }
            *(bf16x4*)(&h0s[g * 512 + sub]) = pk;
        }
    }
    __syncthreads();   // h0 complete

    // ================= Layer 1 (A=W1 rows, B=h0 granules g = ks*2+nt) =======
    f32x4 acc1[2][2];   // [ot][nt] — 16 regs
    #pragma unroll
    for (int ot = 0; ot < 2; ++ot)
        #pragma unroll
        for (int nt = 0; nt < 2; ++nt)
            acc1[ot][nt] = (f32x4){0.f, 0.f, 0.f, 0.f};

    a0 = q0; a1 = q1;
    #pragma unroll
    for (int ks = 0; ks < 16; ++ks) {
        bf16x8 na0 = a0, na1 = a1;
        if (ks < 15) {
            na0 = *(const bf16x8*)(w1r + (ks + 1) * 32);
            na1 = *(const bf16x8*)(w1r + 16 * NH0 + (ks + 1) * 32);
        }
        #pragma unroll
        for (int nt = 0; nt < 2; ++nt) {
            bf16x8 bf = *(const bf16x8*)(h0s + ((ks * 2 + nt) * 64 + lane) * 8);
            acc1[0][nt] = __builtin_amdgcn_mfma_f32_16x16x32_bf16(a0, bf, acc1[0][nt], 0, 0, 0);
            acc1[1][nt] = __builtin_amdgcn_mfma_f32_16x16x32_bf16(a1, bf, acc1[1][nt], 0, 0, 0);
        }
        a0 = na0; a1 = na1;
    }

    // ---------------- Layer 2 ----------------------------------------------
    // acc1: o = (2w+ot)*16 + 4*l4 + r, m = nt*16 + l15
    float part[2] = {0.f, 0.f};
    #pragma unroll
    for (int ot = 0; ot < 2; ++ot) {
        const int ob = (2 * w + ot) * 16 + 4 * l4;
        const f32x4 b1v = *(const f32x4*)(b1 + c * NH1 + ob);
        const f32x4 w2v = *(const f32x4*)(W2 + c * NH1 + ob);
        #pragma unroll
        for (int r = 0; r < 4; ++r) {
            #pragma unroll
            for (int nt = 0; nt < 2; ++nt) {
                float v = acc1[ot][nt][r] + b1v[r];
                v = v > 0.f ? v : 0.f;
                part[nt] += v * w2v[r];
            }
        }
    }
    #pragma unroll
    for (int nt = 0; nt < 2; ++nt) {
        part[nt] += __shfl_xor(part[nt], 16, 64);
        part[nt] += __shfl_xor(part[nt], 32, 64);
    }
    if (l4 == 0) {
        #pragma unroll
        for (int nt = 0; nt < 2; ++nt)
            red[w][nt * 16 + l15] = part[nt];
    }
    __syncthreads();

    if (tid < BTM) {
        float s = 0.f;
        #pragma unroll
        for (int ww = 0; ww < 8; ++ww) s += red[ww][tid];
        s += b2[c];
        out[(size_t)(row0 + tid) * CNUM + c] = s;
    }
}

// ---------------------------------------------------------------------------
// Fallback (fp32 loads, no workspace) in case ws_size < WS_NEED. BT=64 geom.
// ---------------------------------------------------------------------------
__device__ __forceinline__ bf16x8 ld_cvt8(const float* __restrict__ p) {
    f32x8 v = *(const f32x8*)p;
    bf16x8 r;
    #pragma unroll
    for (int i = 0; i < 8; ++i) r[i] = (__bf16)v[i];
    return r;
}

#define P0 (NH0 + 8)

__global__ __launch_bounds__(NTHREADS, 4)
void confounder_fused(const float* __restrict__ x,
                      const float* __restrict__ W0,
                      const float* __restrict__ b0,
                      const float* __restrict__ W1,
                      const float* __restrict__ b1,
                      const float* __restrict__ W2,
                      const float* __restrict__ b2,
                      float* __restrict__ out) {
    __shared__ __align__(16) __bf16 h0s[BT * P0];
    __shared__ float red[8][BT];

    const int c    = blockIdx.x & 7;
    const int mb   = blockIdx.x >> 3;
    const int row0 = mb * BT;
    const int tid  = threadIdx.x;
    const int w    = tid >> 6;
    const int lane = tid & 63;
    const int l15  = lane & 15;
    const int l4   = lane >> 4;

    f32x4 acc0[4][4];
    #pragma unroll
    for (int mt = 0; mt < 4; ++mt)
        #pragma unroll
        for (int nt = 0; nt < 4; ++nt)
            acc0[mt][nt] = (f32x4){0.f, 0.f, 0.f, 0.f};

    const float* xb  = x  + (size_t)(row0 + l15) * DIN + 8 * l4;
    const float* w0b = W0 + ((size_t)c * NH0 + w * 64 + l15) * DIN + 8 * l4;

    #pragma unroll
    for (int ks = 0; ks < DIN / 32; ++ks) {
        bf16x8 a[4];
        #pragma unroll
        for (int mt = 0; mt < 4; ++mt)
            a[mt] = ld_cvt8(xb + mt * 16 * DIN + ks * 32);
        #pragma unroll
        for (int nt = 0; nt < 4; ++nt) {
            bf16x8 bf = ld_cvt8(w0b + nt * 16 * DIN + ks * 32);
            #pragma unroll
            for (int mt = 0; mt < 4; ++mt)
                acc0[mt][nt] = __builtin_amdgcn_mfma_f32_16x16x32_bf16(a[mt], bf, acc0[mt][nt], 0, 0, 0);
        }
    }
    #pragma unroll
    for (int nt = 0; nt < 4; ++nt) {
        const int n    = (w * 4 + nt) * 16 + l15;
        const float bv = b0[c * NH0 + n];
        #pragma unroll
        for (int mt = 0; mt < 4; ++mt)
            #pragma unroll
            for (int r = 0; r < 4; ++r) {
                float v = acc0[mt][nt][r] + bv;
                v = v > 0.f ? v : 0.f;
                h0s[(mt * 16 + l4 * 4 + r) * P0 + n] = (__bf16)v;
            }
    }
    __syncthreads();

    f32x4 acc1[2][4];
    #pragma unroll
    for (int ot = 0; ot < 2; ++ot)
        #pragma unroll
        for (int nt = 0; nt < 4; ++nt)
            acc1[ot][nt] = (f32x4){0.f, 0.f, 0.f, 0.f};

    const float* w1b = W1 + ((size_t)c * NH1 + w * 32 + l15) * NH0 + 8 * l4;

    #pragma unroll
    for (int ks = 0; ks < NH0 / 32; ++ks) {
        bf16x8 a[2];
        #pragma unroll
        for (int ot = 0; ot < 2; ++ot)
            a[ot] = ld_cvt8(w1b + ot * 16 * NH0 + ks * 32);
        #pragma unroll
        for (int nt = 0; nt < 4; ++nt) {
            bf16x8 bf = *(const bf16x8*)(&h0s[(nt * 16 + l15) * P0 + ks * 32 + 8 * l4]);
            #pragma unroll
            for (int ot = 0; ot < 2; ++ot)
                acc1[ot][nt] = __builtin_amdgcn_mfma_f32_16x16x32_bf16(a[ot], bf, acc1[ot][nt], 0, 0, 0);
        }
    }

    float part[4] = {0.f, 0.f, 0.f, 0.f};
    #pragma unroll
    for (int ot = 0; ot < 2; ++ot)
        #pragma unroll
        for (int r = 0; r < 4; ++r) {
            const int o     = (2 * w + ot) * 16 + l4 * 4 + r;
            const float b1v = b1[c * NH1 + o];
            const float w2v = W2[c * NH1 + o];
            #pragma unroll
            for (int nt = 0; nt < 4; ++nt) {
                float v = acc1[ot][nt][r] + b1v;
                v = v > 0.f ? v : 0.f;
                part[nt] += v * w2v;
            }
        }
    #pragma unroll
    for (int nt = 0; nt < 4; ++nt) {
        part[nt] += __shfl_xor(part[nt], 16, 64);
        part[nt] += __shfl_xor(part[nt], 32, 64);
    }
    if (l4 == 0) {
        #pragma unroll
        for (int nt = 0; nt < 4; ++nt)
            red[w][nt * 16 + l15] = part[nt];
    }
    __syncthreads();

    if (tid < BT) {
        float s = 0.f;
        #pragma unroll
        for (int ww = 0; ww < 8; ++ww) s += red[ww][tid];
        s += b2[c];
        out[(size_t)(row0 + tid) * CNUM + c] = s;
    }
}

extern "C" void kernel_launch(void* const* d_in, const int* in_sizes, int n_in,
                              void* d_out, int out_size, void* d_ws, size_t ws_size,
                              hipStream_t stream) {
    const float* x  = (const float*)d_in[0];
    const float* W0 = (const float*)d_in[1];
    const float* b0 = (const float*)d_in[2];
    const float* W1 = (const float*)d_in[3];
    const float* b1 = (const float*)d_in[4];
    const float* W2 = (const float*)d_in[5];
    const float* b2 = (const float*)d_in[6];
    float* out = (float*)d_out;

    if (ws_size >= WS_NEED) {
        __bf16* ws = (__bf16*)d_ws;
        cvt_bf16<<<dim3((X_ELEMS + W0_ELEMS + W1_ELEMS) / 8 / 256), dim3(256), 0, stream>>>(x, W0, W1, ws);
        confounder_main<<<dim3((BATCH / BTM) * CNUM), dim3(NTHREADS), 0, stream>>>(ws, b0, b1, W2, b2, out);
    } else {
        confounder_fused<<<dim3((BATCH / BT) * CNUM), dim3(NTHREADS), 0, stream>>>(x, W0, b0, W1, b1, W2, b2, out);
    }
}

// Round 4
// 205.543 us; speedup vs baseline: 1.5522x; 1.5522x over previous
//
#include <hip/hip_runtime.h>

// Problem constants (from reference)
#define BATCH 16384
#define CNUM  8
#define DIN   256
#define NH0   512
#define NH1   256

#define BT       64            // batch rows per block
#define NTHREADS 512           // 8 waves

#define X_ELEMS  (BATCH * DIN)        // 4194304
#define W0_ELEMS (CNUM * NH0 * DIN)   // 1048576
#define W1_ELEMS (CNUM * NH1 * NH0)   // 1048576
#define WS_NEED  ((size_t)(X_ELEMS + W0_ELEMS + W1_ELEMS) * 2)  // 12.6 MB bf16

typedef __bf16 bf16x8 __attribute__((ext_vector_type(8)));
typedef __bf16 bf16x4 __attribute__((ext_vector_type(4)));
typedef float  f32x4  __attribute__((ext_vector_type(4)));
typedef float  f32x8  __attribute__((ext_vector_type(8)));

// ---------------------------------------------------------------------------
// Prep: fp32 -> bf16 for x, W0, W1 into ws.  786432 chunks x 8 elems.
// ---------------------------------------------------------------------------
__global__ __launch_bounds__(256)
void cvt_bf16(const float* __restrict__ x, const float* __restrict__ W0,
              const float* __restrict__ W1, __bf16* __restrict__ ws) {
    const int i = blockIdx.x * 256 + threadIdx.x;   // chunk of 8 elems
    const float* src;
    __bf16* dst;
    int off;
    if (i < X_ELEMS / 8)                 { src = x;  dst = ws;                        off = i * 8; }
    else if (i < (X_ELEMS + W0_ELEMS)/8) { src = W0; dst = ws + X_ELEMS;             off = (i - X_ELEMS/8) * 8; }
    else                                 { src = W1; dst = ws + X_ELEMS + W0_ELEMS;  off = (i - (X_ELEMS + W0_ELEMS)/8) * 8; }
    f32x8 v = *(const f32x8*)(src + off);
    bf16x8 r;
    #pragma unroll
    for (int j = 0; j < 8; ++j) r[j] = (__bf16)v[j];
    *(bf16x8*)(dst + off) = r;
}

// ---------------------------------------------------------------------------
// Main fused kernel (bf16 path), BT=64, deep software pipeline.
// grid = (BATCH/BT)*CNUM; c = blockIdx&7 (XCD round-robin -> W[c] L2-resident).
//
// LDS h0s = 64 granules x 512 elems (1 KB), granule g = h*32 + bt*8 + kw
//   (h = n>>8 half, bt = m>>4, kw = (n>>5)&7). Frag-major -> layer-1
//   ds_read_b128 is lane-contiguous, conflict-free.
// xs (frag-major x tile, 32 KB) aliases granules 32..63 during layer 0.
//
// Latency engineering (round-3 lesson: per-wave ILP >> occupancy):
//  - W0/W1 global loads: explicit depth-4 ring (statically unrolled arrays),
//    prologues issued across barriers/epilogues -> ~300+ cyc of cover.
//  - LDS B-fragments: ping-pong, read one k-step ahead.
//  - s_setprio(1) around MFMA clusters.
// ---------------------------------------------------------------------------
__global__ __launch_bounds__(NTHREADS, 4)
void confounder_main(const __bf16* __restrict__ ws,
                     const float* __restrict__ b0,
                     const float* __restrict__ b1,
                     const float* __restrict__ W2,
                     const float* __restrict__ b2,
                     float* __restrict__ out) {
    __shared__ __align__(16) __bf16 h0s[BT * NH0];  // 64 KB granule-major
    __shared__ float red[8][BT];                    // 2 KB
    __bf16* xs = h0s + 32 * 512;                    // upper 32 KB alias for x tile

    const __bf16* xbf = ws;
    const __bf16* w0b = ws + X_ELEMS;
    const __bf16* w1b = ws + X_ELEMS + W0_ELEMS;

    const int c    = blockIdx.x & 7;
    const int mb   = blockIdx.x >> 3;
    const int row0 = mb * BT;

    const int tid  = threadIdx.x;
    const int w    = tid >> 6;    // wave 0..7
    const int lane = tid & 63;
    const int l15  = lane & 15;
    const int l4   = lane >> 4;   // 0..3

    // ---- stage x tile into LDS (granules 32..63), frag-major --------------
    #pragma unroll
    for (int q = 0; q < 4; ++q) {
        const int p  = w * 4 + q;
        const int mt = p >> 3, ks = p & 7;
        bf16x8 v = *(const bf16x8*)(xbf + (size_t)(row0 + mt * 16 + l15) * DIN + ks * 32 + 8 * l4);
        *(bf16x8*)(xs + (p * 64 + lane) * 8) = v;
    }

    // W0 row bases: half h covers n = h*256 + w*32 + at*16 + l15
    const __bf16* w0r  = w0b + ((size_t)c * NH0 + w * 32 + l15) * DIN + 8 * l4;
    const __bf16* w0r1 = w0r + 256 * DIN;

    // ---- half-0 W ring prologue (depth 4), issued before the barrier ------
    bf16x8 awA[8][2];
    #pragma unroll
    for (int kp = 0; kp < 4; ++kp) {
        awA[kp][0] = *(const bf16x8*)(w0r + kp * 32);
        awA[kp][1] = *(const bf16x8*)(w0r + 16 * DIN + kp * 32);
    }
    __syncthreads();

    f32x4 acc[2][4];   // [at][bt]

    // ================= Layer 0, half h = 0 (n in [0,256)) ==================
    #pragma unroll
    for (int at = 0; at < 2; ++at)
        #pragma unroll
        for (int bt = 0; bt < 4; ++bt)
            acc[at][bt] = (f32x4){0.f, 0.f, 0.f, 0.f};

    bf16x8 bb[2][4];   // LDS B ping-pong
    #pragma unroll
    for (int bt = 0; bt < 4; ++bt)
        bb[0][bt] = *(const bf16x8*)(xs + ((bt * 8 + 0) * 64 + lane) * 8);

    #pragma unroll
    for (int ks = 0; ks < 8; ++ks) {
        if (ks + 4 < 8) {
            awA[ks + 4][0] = *(const bf16x8*)(w0r + (ks + 4) * 32);
            awA[ks + 4][1] = *(const bf16x8*)(w0r + 16 * DIN + (ks + 4) * 32);
        }
        if (ks < 7) {
            #pragma unroll
            for (int bt = 0; bt < 4; ++bt)
                bb[(ks + 1) & 1][bt] = *(const bf16x8*)(xs + ((bt * 8 + ks + 1) * 64 + lane) * 8);
        }
        __builtin_amdgcn_s_setprio(1);
        #pragma unroll
        for (int bt = 0; bt < 4; ++bt) {
            acc[0][bt] = __builtin_amdgcn_mfma_f32_16x16x32_bf16(awA[ks][0], bb[ks & 1][bt], acc[0][bt], 0, 0, 0);
            acc[1][bt] = __builtin_amdgcn_mfma_f32_16x16x32_bf16(awA[ks][1], bb[ks & 1][bt], acc[1][bt], 0, 0, 0);
        }
        __builtin_amdgcn_s_setprio(0);
    }

    // ---- half-1 W ring prologue (depth 4), in flight during epilogue-0 ----
    bf16x8 awB[8][2];
    #pragma unroll
    for (int kp = 0; kp < 4; ++kp) {
        awB[kp][0] = *(const bf16x8*)(w0r1 + kp * 32);
        awB[kp][1] = *(const bf16x8*)(w0r1 + 16 * DIN + kp * 32);
    }

    // epilogue half 0 -> granules g = bt*8 + w (lower 32 KB); xs untouched
    #pragma unroll
    for (int at = 0; at < 2; ++at) {
        const int nb = w * 32 + at * 16 + 4 * l4;
        const f32x4 b4 = *(const f32x4*)(b0 + c * NH0 + nb);
        const int sub = (at * 2 + (l4 >> 1)) * 128 + l15 * 8 + 4 * (l4 & 1);
        #pragma unroll
        for (int bt = 0; bt < 4; ++bt) {
            const int g = bt * 8 + w;
            bf16x4 pk;
            #pragma unroll
            for (int r = 0; r < 4; ++r) {
                float v = acc[at][bt][r] + b4[r];
                v = v > 0.f ? v : 0.f;
                pk[r] = (__bf16)v;
            }
            *(bf16x4*)(&h0s[g * 512 + sub]) = pk;
        }
    }

    // ================= Layer 0, half h = 1 (n in [256,512)) ================
    #pragma unroll
    for (int at = 0; at < 2; ++at)
        #pragma unroll
        for (int bt = 0; bt < 4; ++bt)
            acc[at][bt] = (f32x4){0.f, 0.f, 0.f, 0.f};

    #pragma unroll
    for (int bt = 0; bt < 4; ++bt)
        bb[0][bt] = *(const bf16x8*)(xs + ((bt * 8 + 0) * 64 + lane) * 8);

    #pragma unroll
    for (int ks = 0; ks < 8; ++ks) {
        if (ks + 4 < 8) {
            awB[ks + 4][0] = *(const bf16x8*)(w0r1 + (ks + 4) * 32);
            awB[ks + 4][1] = *(const bf16x8*)(w0r1 + 16 * DIN + (ks + 4) * 32);
        }
        if (ks < 7) {
            #pragma unroll
            for (int bt = 0; bt < 4; ++bt)
                bb[(ks + 1) & 1][bt] = *(const bf16x8*)(xs + ((bt * 8 + ks + 1) * 64 + lane) * 8);
        }
        __builtin_amdgcn_s_setprio(1);
        #pragma unroll
        for (int bt = 0; bt < 4; ++bt) {
            acc[0][bt] = __builtin_amdgcn_mfma_f32_16x16x32_bf16(awB[ks][0], bb[ks & 1][bt], acc[0][bt], 0, 0, 0);
            acc[1][bt] = __builtin_amdgcn_mfma_f32_16x16x32_bf16(awB[ks][1], bb[ks & 1][bt], acc[1][bt], 0, 0, 0);
        }
        __builtin_amdgcn_s_setprio(0);
    }

    // ---- W1 ring prologue (depth 4), rides through the barriers below -----
    const __bf16* w1r = w1b + ((size_t)c * NH1 + w * 32 + l15) * NH0 + 8 * l4;
    bf16x8 aw1[16][2];
    #pragma unroll
    for (int kp = 0; kp < 4; ++kp) {
        aw1[kp][0] = *(const bf16x8*)(w1r + kp * 32);
        aw1[kp][1] = *(const bf16x8*)(w1r + 16 * NH0 + kp * 32);
    }

    __syncthreads();   // all waves done reading xs before granules 32..63 write

    // epilogue half 1 -> granules g = 32 + bt*8 + w
    #pragma unroll
    for (int at = 0; at < 2; ++at) {
        const int nb = 256 + w * 32 + at * 16 + 4 * l4;
        const f32x4 b4 = *(const f32x4*)(b0 + c * NH0 + nb);
        const int sub = (at * 2 + (l4 >> 1)) * 128 + l15 * 8 + 4 * (l4 & 1);
        #pragma unroll
        for (int bt = 0; bt < 4; ++bt) {
            const int g = 32 + bt * 8 + w;
            bf16x4 pk;
            #pragma unroll
            for (int r = 0; r < 4; ++r) {
                float v = acc[at][bt][r] + b4[r];
                v = v > 0.f ? v : 0.f;
                pk[r] = (__bf16)v;
            }
            *(bf16x4*)(&h0s[g * 512 + sub]) = pk;
        }
    }
    __syncthreads();   // h0 complete

    // ================= Layer 1 (A=W1 rows, B=h0 granules) ===================
    // granule for (ks, nt): g = (ks>>3)*32 + nt*8 + (ks&7)
    f32x4 acc1[2][4];   // [ot][nt]
    #pragma unroll
    for (int ot = 0; ot < 2; ++ot)
        #pragma unroll
        for (int nt = 0; nt < 4; ++nt)
            acc1[ot][nt] = (f32x4){0.f, 0.f, 0.f, 0.f};

    #pragma unroll
    for (int nt = 0; nt < 4; ++nt)
        bb[0][nt] = *(const bf16x8*)(h0s + ((nt * 8 + 0) * 64 + lane) * 8);

    #pragma unroll
    for (int ks = 0; ks < 16; ++ks) {
        if (ks + 4 < 16) {
            aw1[ks + 4][0] = *(const bf16x8*)(w1r + (ks + 4) * 32);
            aw1[ks + 4][1] = *(const bf16x8*)(w1r + 16 * NH0 + (ks + 4) * 32);
        }
        if (ks < 15) {
            const int kn = ks + 1;
            const int gb = ((kn >> 3) * 32 + (kn & 7));
            #pragma unroll
            for (int nt = 0; nt < 4; ++nt)
                bb[kn & 1][nt] = *(const bf16x8*)(h0s + ((gb + nt * 8) * 64 + lane) * 8);
        }
        __builtin_amdgcn_s_setprio(1);
        #pragma unroll
        for (int nt = 0; nt < 4; ++nt) {
            acc1[0][nt] = __builtin_amdgcn_mfma_f32_16x16x32_bf16(aw1[ks][0], bb[ks & 1][nt], acc1[0][nt], 0, 0, 0);
            acc1[1][nt] = __builtin_amdgcn_mfma_f32_16x16x32_bf16(aw1[ks][1], bb[ks & 1][nt], acc1[1][nt], 0, 0, 0);
        }
        __builtin_amdgcn_s_setprio(0);
    }

    // ---------------- Layer 2 ----------------------------------------------
    // acc1: o = (2w+ot)*16 + 4*l4 + r, m = nt*16 + l15
    float part[4] = {0.f, 0.f, 0.f, 0.f};
    #pragma unroll
    for (int ot = 0; ot < 2; ++ot) {
        const int ob = (2 * w + ot) * 16 + 4 * l4;
        const f32x4 b1v = *(const f32x4*)(b1 + c * NH1 + ob);
        const f32x4 w2v = *(const f32x4*)(W2 + c * NH1 + ob);
        #pragma unroll
        for (int r = 0; r < 4; ++r) {
            #pragma unroll
            for (int nt = 0; nt < 4; ++nt) {
                float v = acc1[ot][nt][r] + b1v[r];
                v = v > 0.f ? v : 0.f;
                part[nt] += v * w2v[r];
            }
        }
    }
    #pragma unroll
    for (int nt = 0; nt < 4; ++nt) {
        part[nt] += __shfl_xor(part[nt], 16, 64);
        part[nt] += __shfl_xor(part[nt], 32, 64);
    }
    if (l4 == 0) {
        #pragma unroll
        for (int nt = 0; nt < 4; ++nt)
            red[w][nt * 16 + l15] = part[nt];
    }
    __syncthreads();

    if (tid < BT) {
        float s = 0.f;
        #pragma unroll
        for (int ww = 0; ww < 8; ++ww) s += red[ww][tid];
        s += b2[c];
        out[(size_t)(row0 + tid) * CNUM + c] = s;
    }
}

// ---------------------------------------------------------------------------
// Fallback (fp32 loads, no workspace) in case ws_size < WS_NEED. BT=64 geom.
// ---------------------------------------------------------------------------
__device__ __forceinline__ bf16x8 ld_cvt8(const float* __restrict__ p) {
    f32x8 v = *(const f32x8*)p;
    bf16x8 r;
    #pragma unroll
    for (int i = 0; i < 8; ++i) r[i] = (__bf16)v[i];
    return r;
}

#define P0 (NH0 + 8)

__global__ __launch_bounds__(NTHREADS, 4)
void confounder_fused(const float* __restrict__ x,
                      const float* __restrict__ W0,
                      const float* __restrict__ b0,
                      const float* __restrict__ W1,
                      const float* __restrict__ b1,
                      const float* __restrict__ W2,
                      const float* __restrict__ b2,
                      float* __restrict__ out) {
    __shared__ __align__(16) __bf16 h0s[BT * P0];
    __shared__ float red[8][BT];

    const int c    = blockIdx.x & 7;
    const int mb   = blockIdx.x >> 3;
    const int row0 = mb * BT;
    const int tid  = threadIdx.x;
    const int w    = tid >> 6;
    const int lane = tid & 63;
    const int l15  = lane & 15;
    const int l4   = lane >> 4;

    f32x4 acc0[4][4];
    #pragma unroll
    for (int mt = 0; mt < 4; ++mt)
        #pragma unroll
        for (int nt = 0; nt < 4; ++nt)
            acc0[mt][nt] = (f32x4){0.f, 0.f, 0.f, 0.f};

    const float* xb  = x  + (size_t)(row0 + l15) * DIN + 8 * l4;
    const float* w0b = W0 + ((size_t)c * NH0 + w * 64 + l15) * DIN + 8 * l4;

    #pragma unroll
    for (int ks = 0; ks < DIN / 32; ++ks) {
        bf16x8 a[4];
        #pragma unroll
        for (int mt = 0; mt < 4; ++mt)
            a[mt] = ld_cvt8(xb + mt * 16 * DIN + ks * 32);
        #pragma unroll
        for (int nt = 0; nt < 4; ++nt) {
            bf16x8 bf = ld_cvt8(w0b + nt * 16 * DIN + ks * 32);
            #pragma unroll
            for (int mt = 0; mt < 4; ++mt)
                acc0[mt][nt] = __builtin_amdgcn_mfma_f32_16x16x32_bf16(a[mt], bf, acc0[mt][nt], 0, 0, 0);
        }
    }
    #pragma unroll
    for (int nt = 0; nt < 4; ++nt) {
        const int n    = (w * 4 + nt) * 16 + l15;
        const float bv = b0[c * NH0 + n];
        #pragma unroll
        for (int mt = 0; mt < 4; ++mt)
            #pragma unroll
            for (int r = 0; r < 4; ++r) {
                float v = acc0[mt][nt][r] + bv;
                v = v > 0.f ? v : 0.f;
                h0s[(mt * 16 + l4 * 4 + r) * P0 + n] = (__bf16)v;
            }
    }
    __syncthreads();

    f32x4 acc1[2][4];
    #pragma unroll
    for (int ot = 0; ot < 2; ++ot)
        #pragma unroll
        for (int nt = 0; nt < 4; ++nt)
            acc1[ot][nt] = (f32x4){0.f, 0.f, 0.f, 0.f};

    const float* w1b = W1 + ((size_t)c * NH1 + w * 32 + l15) * NH0 + 8 * l4;

    #pragma unroll
    for (int ks = 0; ks < NH0 / 32; ++ks) {
        bf16x8 a[2];
        #pragma unroll
        for (int ot = 0; ot < 2; ++ot)
            a[ot] = ld_cvt8(w1b + ot * 16 * NH0 + ks * 32);
        #pragma unroll
        for (int nt = 0; nt < 4; ++nt) {
            bf16x8 bf = *(const bf16x8*)(&h0s[(nt * 16 + l15) * P0 + ks * 32 + 8 * l4]);
            #pragma unroll
            for (int ot = 0; ot < 2; ++ot)
                acc1[ot][nt] = __builtin_amdgcn_mfma_f32_16x16x32_bf16(a[ot], bf, acc1[ot][nt], 0, 0, 0);
        }
    }

    float part[4] = {0.f, 0.f, 0.f, 0.f};
    #pragma unroll
    for (int ot = 0; ot < 2; ++ot)
        #pragma unroll
        for (int r = 0; r < 4; ++r) {
            const int o     = (2 * w + ot) * 16 + l4 * 4 + r;
            const float b1v = b1[c * NH1 + o];
            const float w2v = W2[c * NH1 + o];
            #pragma unroll
            for (int nt = 0; nt < 4; ++nt) {
                float v = acc1[ot][nt][r] + b1v;
                v = v > 0.f ? v : 0.f;
                part[nt] += v * w2v;
            }
        }
    #pragma unroll
    for (int nt = 0; nt < 4; ++nt) {
        part[nt] += __shfl_xor(part[nt], 16, 64);
        part[nt] += __shfl_xor(part[nt], 32, 64);
    }
    if (l4 == 0) {
        #pragma unroll
        for (int nt = 0; nt < 4; ++nt)
            red[w][nt * 16 + l15] = part[nt];
    }
    __syncthreads();

    if (tid < BT) {
        float s = 0.f;
        #pragma unroll
        for (int ww = 0; ww < 8; ++ww) s += red[ww][tid];
        s += b2[c];
        out[(size_t)(row0 + tid) * CNUM + c] = s;
    }
}

extern "C" void kernel_launch(void* const* d_in, const int* in_sizes, int n_in,
                              void* d_out, int out_size, void* d_ws, size_t ws_size,
                              hipStream_t stream) {
    const float* x  = (const float*)d_in[0];
    const float* W0 = (const float*)d_in[1];
    const float* b0 = (const float*)d_in[2];
    const float* W1 = (const float*)d_in[3];
    const float* b1 = (const float*)d_in[4];
    const float* W2 = (const float*)d_in[5];
    const float* b2 = (const float*)d_in[6];
    float* out = (float*)d_out;

    if (ws_size >= WS_NEED) {
        __bf16* ws = (__bf16*)d_ws;
        cvt_bf16<<<dim3((X_ELEMS + W0_ELEMS + W1_ELEMS) / 8 / 256), dim3(256), 0, stream>>>(x, W0, W1, ws);
        confounder_main<<<dim3((BATCH / BT) * CNUM), dim3(NTHREADS), 0, stream>>>(ws, b0, b1, W2, b2, out);
    } else {
        confounder_fused<<<dim3((BATCH / BT) * CNUM), dim3(NTHREADS), 0, stream>>>(x, W0, b0, W1, b1, W2, b2, out);
    }
}